// Round 2
// baseline (118098.633 us; speedup 1.0000x reference)
//
#include <hip/hip_runtime.h>
#include <math.h>

#define NB 8
#define HID 512

// ---------------------------------------------------------------------------
// helpers
// ---------------------------------------------------------------------------
__device__ __forceinline__ float sigf(float x) { return 1.0f / (1.0f + __expf(-x)); }
__device__ __forceinline__ float tanhf_(float x) {
    // tanh(x) = 2*sigmoid(2x) - 1 ; saturates correctly for large |x|
    return 2.0f / (1.0f + __expf(-2.0f * x)) - 1.0f;
}

// ---------------------------------------------------------------------------
// 0) zero sync flags (every launch: graph replays reuse ws)
// ---------------------------------------------------------------------------
__global__ void init_flags_kernel(unsigned int* flags) { flags[threadIdx.x] = 0u; }

// ---------------------------------------------------------------------------
// 1) LayerNorm for one chunk: res_ch[rl] = LN(x[b*4096 + t0 + i]),
//    rl = b*CH + i. One wave per row, 4 rows/block.
// ---------------------------------------------------------------------------
__global__ void ln_kernel(const float* __restrict__ x, const float* __restrict__ gamma,
                          const float* __restrict__ beta, float* __restrict__ res,
                          int t0, int chsh) {
    int wid = threadIdx.x >> 6, lane = threadIdx.x & 63;
    int rl = blockIdx.x * 4 + wid;                    // local row in [0, 8*CH)
    int b = rl >> chsh, i = rl & ((1 << chsh) - 1);
    const float* xr = x + (long long)(b * 4096 + t0 + i) * HID;
    float4 u0 = *(const float4*)(xr + lane * 4);
    float4 u1 = *(const float4*)(xr + 256 + lane * 4);
    float s = u0.x + u0.y + u0.z + u0.w + u1.x + u1.y + u1.z + u1.w;
#pragma unroll
    for (int m = 1; m < 64; m <<= 1) s += __shfl_xor(s, m, 64);
    float mu = s * (1.0f / 512.0f);
    float d[8] = {u0.x - mu, u0.y - mu, u0.z - mu, u0.w - mu,
                  u1.x - mu, u1.y - mu, u1.z - mu, u1.w - mu};
    float q = d[0]*d[0] + d[1]*d[1] + d[2]*d[2] + d[3]*d[3] +
              d[4]*d[4] + d[5]*d[5] + d[6]*d[6] + d[7]*d[7];
#pragma unroll
    for (int m = 1; m < 64; m <<= 1) q += __shfl_xor(q, m, 64);
    float rs = rsqrtf(q * (1.0f / 512.0f) + 1e-5f);
    float4 g0 = *(const float4*)(gamma + lane * 4);
    float4 g1 = *(const float4*)(gamma + 256 + lane * 4);
    float4 b0 = *(const float4*)(beta + lane * 4);
    float4 b1 = *(const float4*)(beta + 256 + lane * 4);
    float* rr = res + (long long)rl * HID;
    float4 o0, o1;
    o0.x = d[0] * rs * g0.x + b0.x; o0.y = d[1] * rs * g0.y + b0.y;
    o0.z = d[2] * rs * g0.z + b0.z; o0.w = d[3] * rs * g0.w + b0.w;
    o1.x = d[4] * rs * g1.x + b1.x; o1.y = d[5] * rs * g1.y + b1.y;
    o1.z = d[6] * rs * g1.z + b1.z; o1.w = d[7] * rs * g1.w + b1.w;
    *(float4*)(rr + lane * 4) = o0;
    *(float4*)(rr + 256 + lane * 4) = o1;
}

// ---------------------------------------------------------------------------
// 2) fp32 GEMM: C[r][j] = sum_k A[r][k]*B[j][k]  (+bias, +activation)
//    K=512. BM=BN=128, BK=16, 256 threads, 8x8 micro-tile.
//    MODE 0: + bias1[j]+bias2[j]    (x_proj)
//    MODE 1: silu(acc + bias1[j])   (gate)
// ---------------------------------------------------------------------------
template <int MODE>
__launch_bounds__(256, 2)
__global__ void gemm_nt(const float* __restrict__ A, const float* __restrict__ B,
                        const float* __restrict__ bias1, const float* __restrict__ bias2,
                        float* __restrict__ C, int N) {
    __shared__ float As[16][132];
    __shared__ float Bs[16][132];
    int tid = threadIdx.x;
    int tx = tid & 15, ty = tid >> 4;
    int r0 = blockIdx.x * 128;
    int j0 = blockIdx.y * 128;
    int arow = tid >> 2, ac = (tid & 3) * 4;

    float acc[8][8] = {};

    for (int kt = 0; kt < 512; kt += 16) {
        float4 a0 = *(const float4*)(A + (long long)(r0 + arow) * 512 + kt + ac);
        float4 a1 = *(const float4*)(A + (long long)(r0 + arow + 64) * 512 + kt + ac);
        float4 b0 = *(const float4*)(B + (long long)(j0 + arow) * 512 + kt + ac);
        float4 b1 = *(const float4*)(B + (long long)(j0 + arow + 64) * 512 + kt + ac);
        __syncthreads();
        As[ac + 0][arow] = a0.x; As[ac + 1][arow] = a0.y;
        As[ac + 2][arow] = a0.z; As[ac + 3][arow] = a0.w;
        As[ac + 0][arow + 64] = a1.x; As[ac + 1][arow + 64] = a1.y;
        As[ac + 2][arow + 64] = a1.z; As[ac + 3][arow + 64] = a1.w;
        Bs[ac + 0][arow] = b0.x; Bs[ac + 1][arow] = b0.y;
        Bs[ac + 2][arow] = b0.z; Bs[ac + 3][arow] = b0.w;
        Bs[ac + 0][arow + 64] = b1.x; Bs[ac + 1][arow + 64] = b1.y;
        Bs[ac + 2][arow + 64] = b1.z; Bs[ac + 3][arow + 64] = b1.w;
        __syncthreads();
#pragma unroll
        for (int kk = 0; kk < 16; kk++) {
            float a[8], bb[8];
            *(float4*)(a)      = *(const float4*)&As[kk][ty * 8];
            *(float4*)(a + 4)  = *(const float4*)&As[kk][ty * 8 + 4];
            *(float4*)(bb)     = *(const float4*)&Bs[kk][tx * 8];
            *(float4*)(bb + 4) = *(const float4*)&Bs[kk][tx * 8 + 4];
#pragma unroll
            for (int i = 0; i < 8; i++)
#pragma unroll
                for (int j = 0; j < 8; j++) acc[i][j] += a[i] * bb[j];
        }
    }

    float bv[8];
#pragma unroll
    for (int jj = 0; jj < 8; jj++) {
        int j = j0 + tx * 8 + jj;
        bv[jj] = (MODE == 0) ? (bias1[j] + bias2[j]) : bias1[j];
    }
#pragma unroll
    for (int ii = 0; ii < 8; ii++) {
        long long r = r0 + ty * 8 + ii;
        float* crow = C + r * (long long)N + j0 + tx * 8;
        float v[8];
#pragma unroll
        for (int jj = 0; jj < 8; jj++) {
            float tv = acc[ii][jj] + bv[jj];
            if (MODE == 1) tv = tv * sigf(tv);
            v[jj] = tv;
        }
        float4 o0, o1;
        o0.x = v[0]; o0.y = v[1]; o0.z = v[2]; o0.w = v[3];
        o1.x = v[4]; o1.y = v[5]; o1.z = v[6]; o1.w = v[7];
        *(float4*)(crow) = o0;
        *(float4*)(crow + 4) = o1;
    }
}

// ---------------------------------------------------------------------------
// 3) LSTM scan for one chunk. Grid = 256 blocks x 256 threads (1 block/CU,
//    all co-resident). block -> (b = bid&7, w = bid>>3); WG owns h slots
//    [w*16, w*16+16). Thread (kg = tid&15, rq = tid>>4): slot = w*16+rq,
//    all 4 gate rows of that slot, k-window [kg*32, kg*32+32).
//    Per step: 128 FMAs + 16 shuffles; kg==0 lane holds all 4 gate sums ->
//    full cell update locally. NO __syncthreads / LDS in the t-loop.
//    Sync: per-wave flags (4/WG, 128/batch), monotone step counters,
//    double-buffered h. Release fence + atomic flag store; readers spin on
//    flags then acquire fence. Bounded spin + latch: a sync bug degrades to
//    a wrong answer, never a hang.
// ---------------------------------------------------------------------------
__launch_bounds__(256, 1)
__global__ void scan_kernel(const float* __restrict__ W_hh,   // [2048][512]
                            const float* __restrict__ xp,     // [8*CH][2048]
                            const float* __restrict__ resv,   // [8*CH][512]
                            const float* __restrict__ gatev,  // [8*CH][512]
                            float* __restrict__ out,          // d_out
                            float* __restrict__ h_buf,        // [2][8][512]
                            float* __restrict__ c_buf,        // [8][512]
                            unsigned int* __restrict__ flags, // [8][128]
                            int t0, int chsh) {
    const int CH = 1 << chsh;
    int b = blockIdx.x & 7, w = blockIdx.x >> 3;
    int tid = threadIdx.x;
    int kg = tid & 15, rq = tid >> 4;
    int lane = tid & 63, wave = tid >> 6;
    int slot = w * 16 + rq;            // h index owned by this thread group

    // wreg[g][j] = W_hh[g*512 + slot][kg*32 + j]
    float wreg[4][32];
#pragma unroll
    for (int g = 0; g < 4; g++) {
        const float* wr = W_hh + (long long)((g << 9) + slot) * 512 + (kg << 5);
#pragma unroll
        for (int q = 0; q < 8; q++) {
            float4 u = *(const float4*)(wr + q * 4);
            wreg[g][q * 4 + 0] = u.x; wreg[g][q * 4 + 1] = u.y;
            wreg[g][q * 4 + 2] = u.z; wreg[g][q * 4 + 3] = u.w;
        }
    }

    float c_reg = 0.0f;
    if (t0 > 0 && kg == 0) c_reg = c_buf[(b << 9) + slot];
    bool sync_ok = true;
    const unsigned int* f0 = flags + b * 128 + lane;

    for (int i = 0; i < CH; i++) {
        int t = t0 + i;
        int rl = (b << chsh) + i;

        // prefetch epilogue operands (arrive during the spin)
        float xpv0 = 0, xpv1 = 0, xpv2 = 0, xpv3 = 0, gv = 0, rv = 0;
        if (kg == 0) {
            const float* xr = xp + (long long)rl * 2048 + slot;
            xpv0 = xr[0]; xpv1 = xr[512]; xpv2 = xr[1024]; xpv3 = xr[1536];
            gv = gatev[rl * 512 + slot];
            rv = resv[rl * 512 + slot];
        }

        float acc0 = 0, acc1 = 0, acc2 = 0, acc3 = 0;
        if (t > 0) {
            if (sync_ok) {
                int tries = 0;
                while (true) {
                    unsigned v0 = __hip_atomic_load(f0, __ATOMIC_RELAXED,
                                                    __HIP_MEMORY_SCOPE_AGENT);
                    unsigned v1 = __hip_atomic_load(f0 + 64, __ATOMIC_RELAXED,
                                                    __HIP_MEMORY_SCOPE_AGENT);
                    if (__all(v0 >= (unsigned)t && v1 >= (unsigned)t)) break;
                    if (++tries > (1 << 14)) { sync_ok = false; break; }
                }
                __builtin_amdgcn_fence(__ATOMIC_ACQUIRE, "agent");
            }
            const float* hb = h_buf + ((t - 1) & 1) * (NB * HID) + (b << 9) + (kg << 5);
            float hv[32];
#pragma unroll
            for (int q = 0; q < 8; q++) {
                float4 u = *(const float4*)(hb + q * 4);
                hv[q * 4 + 0] = u.x; hv[q * 4 + 1] = u.y;
                hv[q * 4 + 2] = u.z; hv[q * 4 + 3] = u.w;
            }
#pragma unroll
            for (int j = 0; j < 32; j++) {
                acc0 += hv[j] * wreg[0][j];
                acc1 += hv[j] * wreg[1][j];
                acc2 += hv[j] * wreg[2][j];
                acc3 += hv[j] * wreg[3][j];
            }
            // reduce across the 16 kg lanes (partners are within one wave)
            acc0 += __shfl_xor(acc0, 1, 64); acc0 += __shfl_xor(acc0, 2, 64);
            acc0 += __shfl_xor(acc0, 4, 64); acc0 += __shfl_xor(acc0, 8, 64);
            acc1 += __shfl_xor(acc1, 1, 64); acc1 += __shfl_xor(acc1, 2, 64);
            acc1 += __shfl_xor(acc1, 4, 64); acc1 += __shfl_xor(acc1, 8, 64);
            acc2 += __shfl_xor(acc2, 1, 64); acc2 += __shfl_xor(acc2, 2, 64);
            acc2 += __shfl_xor(acc2, 4, 64); acc2 += __shfl_xor(acc2, 8, 64);
            acc3 += __shfl_xor(acc3, 1, 64); acc3 += __shfl_xor(acc3, 2, 64);
            acc3 += __shfl_xor(acc3, 4, 64); acc3 += __shfl_xor(acc3, 8, 64);
        }

        if (kg == 0) {
            float iv = sigf(acc0 + xpv0);
            float fv = sigf(acc1 + xpv1);
            float gt = tanhf_(acc2 + xpv2);
            float ov = sigf(acc3 + xpv3);
            c_reg = fv * c_reg + iv * gt;
            float h = ov * tanhf_(c_reg);
            out[(long long)((b << 12) + t) * 512 + slot] = h * gv + rv;
            __hip_atomic_store(h_buf + (t & 1) * (NB * HID) + (b << 9) + slot, h,
                               __ATOMIC_RELAXED, __HIP_MEMORY_SCOPE_AGENT);
            if (t == 4095) {
                out[16777216 + (b << 9) + slot] = h;            // hT
                out[16777216 + 4096 + (b << 9) + slot] = c_reg; // cT
            }
            if (i == CH - 1) c_buf[(b << 9) + slot] = c_reg;    // chunk carry
        }
        // order this wave's h-stores (lanes 0/16/32/48) before its flag
        __builtin_amdgcn_fence(__ATOMIC_RELEASE, "agent");
        if (lane == 0)
            __hip_atomic_store(flags + b * 128 + w * 4 + wave, (unsigned)(t + 1),
                               __ATOMIC_RELAXED, __HIP_MEMORY_SCOPE_AGENT);
    }
}

// ---------------------------------------------------------------------------
// launch: chunk T so the workspace fits in ws_size.
// per-chunk floats: res_ch 8*CH*512, gate_ch 8*CH*512, xp_ch 8*CH*2048
//   -> 98304*CH bytes; + carry buffers ~51 KB.
// ---------------------------------------------------------------------------
extern "C" void kernel_launch(void* const* d_in, const int* in_sizes, int n_in,
                              void* d_out, int out_size, void* d_ws, size_t ws_size,
                              hipStream_t stream) {
    const float* x     = (const float*)d_in[0];
    const float* W_ih  = (const float*)d_in[1];
    const float* W_hh  = (const float*)d_in[2];
    const float* b_ih  = (const float*)d_in[3];
    const float* b_hh  = (const float*)d_in[4];
    const float* gamma = (const float*)d_in[5];
    const float* beta  = (const float*)d_in[6];
    const float* W_lin = (const float*)d_in[7];
    const float* b_lin = (const float*)d_in[8];
    float* out = (float*)d_out;

    const size_t small_bytes = (size_t)(8192 + 4096 + 1024) * 4;  // h_buf,c_buf,flags
    int CH = 256;
    for (int cand = 4096; cand >= 256; cand >>= 1) {
        if ((size_t)98304 * cand + small_bytes <= ws_size) { CH = cand; break; }
    }
    int chsh = 31 - __builtin_clz(CH);

    float* ws      = (float*)d_ws;
    float* res_ch  = ws;
    float* gate_ch = res_ch + (size_t)8 * CH * 512;
    float* xp_ch   = gate_ch + (size_t)8 * CH * 512;
    float* h_buf   = xp_ch + (size_t)8 * CH * 2048;
    float* c_buf   = h_buf + 8192;
    unsigned int* flags = (unsigned int*)(c_buf + 4096);

    init_flags_kernel<<<1, 1024, 0, stream>>>(flags);

    int nchunks = 4096 / CH;
    for (int c = 0; c < nchunks; c++) {
        int t0 = c * CH;
        ln_kernel<<<8 * CH / 4, 256, 0, stream>>>(x, gamma, beta, res_ch, t0, chsh);
        gemm_nt<0><<<dim3(8 * CH / 128, 16), 256, 0, stream>>>(res_ch, W_ih, b_ih, b_hh,
                                                               xp_ch, 2048);
        gemm_nt<1><<<dim3(8 * CH / 128, 4), 256, 0, stream>>>(res_ch, W_lin, b_lin, b_lin,
                                                              gate_ch, 512);
        scan_kernel<<<256, 256, 0, stream>>>(W_hh, xp_ch, res_ch, gate_ch, out,
                                             h_buf, c_buf, flags, t0, chsh);
    }
}

// Round 3
// 15854.668 us; speedup vs baseline: 7.4488x; 7.4488x over previous
//
#include <hip/hip_runtime.h>
#include <math.h>

#define NB 8
#define HID 512

// ---------------------------------------------------------------------------
// helpers
// ---------------------------------------------------------------------------
__device__ __forceinline__ float sigf(float x) { return 1.0f / (1.0f + __expf(-x)); }
__device__ __forceinline__ float tanhf_(float x) {
    return 2.0f / (1.0f + __expf(-2.0f * x)) - 1.0f;
}

// ---------------------------------------------------------------------------
// 0) zero sync flags (every launch: graph replays reuse ws)
// ---------------------------------------------------------------------------
__global__ void init_flags_kernel(unsigned int* flags) { flags[threadIdx.x] = 0u; }

// ---------------------------------------------------------------------------
// 1) LayerNorm for one chunk (unchanged from round 2 — verified correct)
// ---------------------------------------------------------------------------
__global__ void ln_kernel(const float* __restrict__ x, const float* __restrict__ gamma,
                          const float* __restrict__ beta, float* __restrict__ res,
                          int t0, int chsh) {
    int wid = threadIdx.x >> 6, lane = threadIdx.x & 63;
    int rl = blockIdx.x * 4 + wid;
    int b = rl >> chsh, i = rl & ((1 << chsh) - 1);
    const float* xr = x + (long long)(b * 4096 + t0 + i) * HID;
    float4 u0 = *(const float4*)(xr + lane * 4);
    float4 u1 = *(const float4*)(xr + 256 + lane * 4);
    float s = u0.x + u0.y + u0.z + u0.w + u1.x + u1.y + u1.z + u1.w;
#pragma unroll
    for (int m = 1; m < 64; m <<= 1) s += __shfl_xor(s, m, 64);
    float mu = s * (1.0f / 512.0f);
    float d[8] = {u0.x - mu, u0.y - mu, u0.z - mu, u0.w - mu,
                  u1.x - mu, u1.y - mu, u1.z - mu, u1.w - mu};
    float q = d[0]*d[0] + d[1]*d[1] + d[2]*d[2] + d[3]*d[3] +
              d[4]*d[4] + d[5]*d[5] + d[6]*d[6] + d[7]*d[7];
#pragma unroll
    for (int m = 1; m < 64; m <<= 1) q += __shfl_xor(q, m, 64);
    float rs = rsqrtf(q * (1.0f / 512.0f) + 1e-5f);
    float4 g0 = *(const float4*)(gamma + lane * 4);
    float4 g1 = *(const float4*)(gamma + 256 + lane * 4);
    float4 b0 = *(const float4*)(beta + lane * 4);
    float4 b1 = *(const float4*)(beta + 256 + lane * 4);
    float* rr = res + (long long)rl * HID;
    float4 o0, o1;
    o0.x = d[0] * rs * g0.x + b0.x; o0.y = d[1] * rs * g0.y + b0.y;
    o0.z = d[2] * rs * g0.z + b0.z; o0.w = d[3] * rs * g0.w + b0.w;
    o1.x = d[4] * rs * g1.x + b1.x; o1.y = d[5] * rs * g1.y + b1.y;
    o1.z = d[6] * rs * g1.z + b1.z; o1.w = d[7] * rs * g1.w + b1.w;
    *(float4*)(rr + lane * 4) = o0;
    *(float4*)(rr + 256 + lane * 4) = o1;
}

// ---------------------------------------------------------------------------
// 2) fp32 GEMM (unchanged from round 2 — verified correct)
// ---------------------------------------------------------------------------
template <int MODE>
__launch_bounds__(256, 2)
__global__ void gemm_nt(const float* __restrict__ A, const float* __restrict__ B,
                        const float* __restrict__ bias1, const float* __restrict__ bias2,
                        float* __restrict__ C, int N) {
    __shared__ float As[16][132];
    __shared__ float Bs[16][132];
    int tid = threadIdx.x;
    int tx = tid & 15, ty = tid >> 4;
    int r0 = blockIdx.x * 128;
    int j0 = blockIdx.y * 128;
    int arow = tid >> 2, ac = (tid & 3) * 4;

    float acc[8][8] = {};

    for (int kt = 0; kt < 512; kt += 16) {
        float4 a0 = *(const float4*)(A + (long long)(r0 + arow) * 512 + kt + ac);
        float4 a1 = *(const float4*)(A + (long long)(r0 + arow + 64) * 512 + kt + ac);
        float4 b0 = *(const float4*)(B + (long long)(j0 + arow) * 512 + kt + ac);
        float4 b1 = *(const float4*)(B + (long long)(j0 + arow + 64) * 512 + kt + ac);
        __syncthreads();
        As[ac + 0][arow] = a0.x; As[ac + 1][arow] = a0.y;
        As[ac + 2][arow] = a0.z; As[ac + 3][arow] = a0.w;
        As[ac + 0][arow + 64] = a1.x; As[ac + 1][arow + 64] = a1.y;
        As[ac + 2][arow + 64] = a1.z; As[ac + 3][arow + 64] = a1.w;
        Bs[ac + 0][arow] = b0.x; Bs[ac + 1][arow] = b0.y;
        Bs[ac + 2][arow] = b0.z; Bs[ac + 3][arow] = b0.w;
        Bs[ac + 0][arow + 64] = b1.x; Bs[ac + 1][arow + 64] = b1.y;
        Bs[ac + 2][arow + 64] = b1.z; Bs[ac + 3][arow + 64] = b1.w;
        __syncthreads();
#pragma unroll
        for (int kk = 0; kk < 16; kk++) {
            float a[8], bb[8];
            *(float4*)(a)      = *(const float4*)&As[kk][ty * 8];
            *(float4*)(a + 4)  = *(const float4*)&As[kk][ty * 8 + 4];
            *(float4*)(bb)     = *(const float4*)&Bs[kk][tx * 8];
            *(float4*)(bb + 4) = *(const float4*)&Bs[kk][tx * 8 + 4];
#pragma unroll
            for (int i = 0; i < 8; i++)
#pragma unroll
                for (int j = 0; j < 8; j++) acc[i][j] += a[i] * bb[j];
        }
    }

    float bv[8];
#pragma unroll
    for (int jj = 0; jj < 8; jj++) {
        int j = j0 + tx * 8 + jj;
        bv[jj] = (MODE == 0) ? (bias1[j] + bias2[j]) : bias1[j];
    }
#pragma unroll
    for (int ii = 0; ii < 8; ii++) {
        long long r = r0 + ty * 8 + ii;
        float* crow = C + r * (long long)N + j0 + tx * 8;
        float v[8];
#pragma unroll
        for (int jj = 0; jj < 8; jj++) {
            float tv = acc[ii][jj] + bv[jj];
            if (MODE == 1) tv = tv * sigf(tv);
            v[jj] = tv;
        }
        float4 o0, o1;
        o0.x = v[0]; o0.y = v[1]; o0.z = v[2]; o0.w = v[3];
        o1.x = v[4]; o1.y = v[5]; o1.z = v[6]; o1.w = v[7];
        *(float4*)(crow) = o0;
        *(float4*)(crow + 4) = o1;
    }
}

// ---------------------------------------------------------------------------
// 3) LSTM scan. 256 WGs x 256 thr (1/CU). b=bid&7, w=bid>>3.
//    Thread (kg=tid&15, rq=tid>>4): slot=w*16+rq, 4 gate rows, k-window
//    [kg*32, kg*32+32). 128 FMAs + 16 shuffles; kg==0 lane does the cell
//    update locally.
//    Sync protocol (NO fences — this was round 2's 28us/step bug; agent
//    fences lower to buffer_wbl2/buffer_inv = per-step L2 writeback storms):
//      producer: h agent-relaxed atomic stores -> s_waitcnt vmcnt(0) ->
//                __syncthreads -> tid0 stores per-WG flag (agent-relaxed)
//      consumer: poll 2 needed per-WG flags/lane (wave __all covers all 32)
//                -> compiler barrier -> h via agent-relaxed u64 atomic loads
//    All shared data bypasses L1/L2 (sc1 -> MALL = single serialization
//    point), so no cache maintenance is needed; vmcnt(0) gives the
//    h-before-flag order (same as LLVM's store-release, minus wbl2).
// ---------------------------------------------------------------------------
__launch_bounds__(256, 1)
__global__ void scan_kernel(const float* __restrict__ W_hh,   // [2048][512]
                            const float* __restrict__ xp,     // [8*CH][2048]
                            const float* __restrict__ resv,   // [8*CH][512]
                            const float* __restrict__ gatev,  // [8*CH][512]
                            float* __restrict__ out,          // d_out
                            float* __restrict__ h_buf,        // [2][8][512]
                            float* __restrict__ c_buf,        // [8][512]
                            unsigned int* __restrict__ flags, // [8][32]
                            int t0, int chsh) {
    const int CH = 1 << chsh;
    int b = blockIdx.x & 7, w = blockIdx.x >> 3;
    int tid = threadIdx.x;
    int kg = tid & 15, rq = tid >> 4;
    int slot = w * 16 + rq;

    // wreg[g][j] = W_hh[g*512 + slot][kg*32 + j]
    float wreg[4][32];
#pragma unroll
    for (int g = 0; g < 4; g++) {
        const float* wr = W_hh + (long long)((g << 9) + slot) * 512 + (kg << 5);
#pragma unroll
        for (int q = 0; q < 8; q++) {
            float4 u = *(const float4*)(wr + q * 4);
            wreg[g][q * 4 + 0] = u.x; wreg[g][q * 4 + 1] = u.y;
            wreg[g][q * 4 + 2] = u.z; wreg[g][q * 4 + 3] = u.w;
        }
    }

    float c_reg = 0.0f;
    if (t0 > 0 && kg == 0) c_reg = c_buf[(b << 9) + slot];
    bool sync_ok = true;
    // this lane's h-window [32kg, 32kg+32) is produced by WGs 2kg and 2kg+1
    const unsigned int* fA = flags + b * 32 + 2 * kg;

    for (int i = 0; i < CH; i++) {
        int t = t0 + i;
        int rl = (b << chsh) + i;

        // prefetch epilogue operands (in flight during poll + matvec)
        float xpv0 = 0, xpv1 = 0, xpv2 = 0, xpv3 = 0, gv = 0, rv = 0;
        if (kg == 0) {
            const float* xr = xp + (long long)rl * 2048 + slot;
            xpv0 = xr[0]; xpv1 = xr[512]; xpv2 = xr[1024]; xpv3 = xr[1536];
            gv = gatev[rl * 512 + slot];
            rv = resv[rl * 512 + slot];
        }

        float acc0 = 0, acc1 = 0, acc2 = 0, acc3 = 0;
        if (t > 0) {
            if (sync_ok) {
                int tries = 0;
                while (true) {
                    unsigned v0 = __hip_atomic_load(fA, __ATOMIC_RELAXED,
                                                    __HIP_MEMORY_SCOPE_AGENT);
                    unsigned v1 = __hip_atomic_load(fA + 1, __ATOMIC_RELAXED,
                                                    __HIP_MEMORY_SCOPE_AGENT);
                    if (__all(v0 >= (unsigned)t && v1 >= (unsigned)t)) break;
                    if (++tries > (1 << 15)) { sync_ok = false; break; }
                }
                asm volatile("" ::: "memory");  // keep h loads below the poll
            }
            const unsigned long long* hb = (const unsigned long long*)
                (h_buf + ((t - 1) & 1) * (NB * HID) + (b << 9) + (kg << 5));
            float hv[32];
#pragma unroll
            for (int q = 0; q < 16; q++) {
                unsigned long long u = __hip_atomic_load(hb + q, __ATOMIC_RELAXED,
                                                         __HIP_MEMORY_SCOPE_AGENT);
                hv[q * 2 + 0] = __uint_as_float((unsigned)u);
                hv[q * 2 + 1] = __uint_as_float((unsigned)(u >> 32));
            }
#pragma unroll
            for (int j = 0; j < 32; j++) {
                acc0 += hv[j] * wreg[0][j];
                acc1 += hv[j] * wreg[1][j];
                acc2 += hv[j] * wreg[2][j];
                acc3 += hv[j] * wreg[3][j];
            }
            acc0 += __shfl_xor(acc0, 1, 64); acc0 += __shfl_xor(acc0, 2, 64);
            acc0 += __shfl_xor(acc0, 4, 64); acc0 += __shfl_xor(acc0, 8, 64);
            acc1 += __shfl_xor(acc1, 1, 64); acc1 += __shfl_xor(acc1, 2, 64);
            acc1 += __shfl_xor(acc1, 4, 64); acc1 += __shfl_xor(acc1, 8, 64);
            acc2 += __shfl_xor(acc2, 1, 64); acc2 += __shfl_xor(acc2, 2, 64);
            acc2 += __shfl_xor(acc2, 4, 64); acc2 += __shfl_xor(acc2, 8, 64);
            acc3 += __shfl_xor(acc3, 1, 64); acc3 += __shfl_xor(acc3, 2, 64);
            acc3 += __shfl_xor(acc3, 4, 64); acc3 += __shfl_xor(acc3, 8, 64);
        }

        float h = 0.0f, ov = 0.0f;
        if (kg == 0) {
            float iv = sigf(acc0 + xpv0);
            float fv = sigf(acc1 + xpv1);
            float gt = tanhf_(acc2 + xpv2);
            ov = sigf(acc3 + xpv3);
            c_reg = fv * c_reg + iv * gt;
            h = ov * tanhf_(c_reg);
            __hip_atomic_store(h_buf + (t & 1) * (NB * HID) + (b << 9) + slot, h,
                               __ATOMIC_RELAXED, __HIP_MEMORY_SCOPE_AGENT);
        }
        // order h-stores (all waves) before the WG's single flag store
        asm volatile("s_waitcnt vmcnt(0)" ::: "memory");
        __syncthreads();
        if (tid == 0)
            __hip_atomic_store(flags + b * 32 + w, (unsigned)(t + 1),
                               __ATOMIC_RELAXED, __HIP_MEMORY_SCOPE_AGENT);
        // non-critical-path stores after the publish
        if (kg == 0) {
            out[(long long)((b << 12) + t) * 512 + slot] = h * gv + rv;
            if (t == 4095) {
                out[16777216 + (b << 9) + slot] = h;            // hT
                out[16777216 + 4096 + (b << 9) + slot] = c_reg; // cT
            }
            if (i == CH - 1) c_buf[(b << 9) + slot] = c_reg;    // chunk carry
        }
    }
}

// ---------------------------------------------------------------------------
// launch: chunk T so the workspace fits ws_size.
// per-chunk floats: 8*CH*512 (res) + 8*CH*512 (gate) + 8*CH*2048 (xp)
// ---------------------------------------------------------------------------
extern "C" void kernel_launch(void* const* d_in, const int* in_sizes, int n_in,
                              void* d_out, int out_size, void* d_ws, size_t ws_size,
                              hipStream_t stream) {
    const float* x     = (const float*)d_in[0];
    const float* W_ih  = (const float*)d_in[1];
    const float* W_hh  = (const float*)d_in[2];
    const float* b_ih  = (const float*)d_in[3];
    const float* b_hh  = (const float*)d_in[4];
    const float* gamma = (const float*)d_in[5];
    const float* beta  = (const float*)d_in[6];
    const float* W_lin = (const float*)d_in[7];
    const float* b_lin = (const float*)d_in[8];
    float* out = (float*)d_out;

    const size_t small_bytes = (size_t)(8192 + 4096 + 256) * 4;  // h_buf,c_buf,flags
    int CH = 256;
    for (int cand = 4096; cand >= 256; cand >>= 1) {
        if ((size_t)98304 * cand + small_bytes <= ws_size) { CH = cand; break; }
    }
    int chsh = 31 - __builtin_clz(CH);

    float* ws      = (float*)d_ws;
    float* res_ch  = ws;
    float* gate_ch = res_ch + (size_t)8 * CH * 512;
    float* xp_ch   = gate_ch + (size_t)8 * CH * 512;
    float* h_buf   = xp_ch + (size_t)8 * CH * 2048;
    float* c_buf   = h_buf + 8192;
    unsigned int* flags = (unsigned int*)(c_buf + 4096);

    init_flags_kernel<<<1, 256, 0, stream>>>(flags);

    int nchunks = 4096 / CH;
    for (int c = 0; c < nchunks; c++) {
        int t0 = c * CH;
        ln_kernel<<<8 * CH / 4, 256, 0, stream>>>(x, gamma, beta, res_ch, t0, chsh);
        gemm_nt<0><<<dim3(8 * CH / 128, 16), 256, 0, stream>>>(res_ch, W_ih, b_ih, b_hh,
                                                               xp_ch, 2048);
        gemm_nt<1><<<dim3(8 * CH / 128, 4), 256, 0, stream>>>(res_ch, W_lin, b_lin, b_lin,
                                                              gate_ch, 512);
        scan_kernel<<<256, 256, 0, stream>>>(W_hh, xp_ch, res_ch, gate_ch, out,
                                             h_buf, c_buf, flags, t0, chsh);
    }
}

// Round 4
// 8258.778 us; speedup vs baseline: 14.2998x; 1.9197x over previous
//
#include <hip/hip_runtime.h>
#include <math.h>

#define NB 8
#define HID 512

// ---------------------------------------------------------------------------
// helpers
// ---------------------------------------------------------------------------
__device__ __forceinline__ float sigf(float x) { return 1.0f / (1.0f + __expf(-x)); }
__device__ __forceinline__ float tanhf_(float x) {
    return 2.0f / (1.0f + __expf(-2.0f * x)) - 1.0f;
}

// ---------------------------------------------------------------------------
// 0) zero the tagged-h buffer (every launch: graph replays reuse ws)
//    h_tag = [2 parity][8 batch][512 slot] u64 -> 8192 entries
// ---------------------------------------------------------------------------
__global__ void init_tags_kernel(unsigned long long* h_tag) {
    h_tag[blockIdx.x * 256 + threadIdx.x] = 0ull;
}

// ---------------------------------------------------------------------------
// 1) LayerNorm for one chunk (unchanged — verified correct)
// ---------------------------------------------------------------------------
__global__ void ln_kernel(const float* __restrict__ x, const float* __restrict__ gamma,
                          const float* __restrict__ beta, float* __restrict__ res,
                          int t0, int chsh) {
    int wid = threadIdx.x >> 6, lane = threadIdx.x & 63;
    int rl = blockIdx.x * 4 + wid;
    int b = rl >> chsh, i = rl & ((1 << chsh) - 1);
    const float* xr = x + (long long)(b * 4096 + t0 + i) * HID;
    float4 u0 = *(const float4*)(xr + lane * 4);
    float4 u1 = *(const float4*)(xr + 256 + lane * 4);
    float s = u0.x + u0.y + u0.z + u0.w + u1.x + u1.y + u1.z + u1.w;
#pragma unroll
    for (int m = 1; m < 64; m <<= 1) s += __shfl_xor(s, m, 64);
    float mu = s * (1.0f / 512.0f);
    float d[8] = {u0.x - mu, u0.y - mu, u0.z - mu, u0.w - mu,
                  u1.x - mu, u1.y - mu, u1.z - mu, u1.w - mu};
    float q = d[0]*d[0] + d[1]*d[1] + d[2]*d[2] + d[3]*d[3] +
              d[4]*d[4] + d[5]*d[5] + d[6]*d[6] + d[7]*d[7];
#pragma unroll
    for (int m = 1; m < 64; m <<= 1) q += __shfl_xor(q, m, 64);
    float rs = rsqrtf(q * (1.0f / 512.0f) + 1e-5f);
    float4 g0 = *(const float4*)(gamma + lane * 4);
    float4 g1 = *(const float4*)(gamma + 256 + lane * 4);
    float4 b0 = *(const float4*)(beta + lane * 4);
    float4 b1 = *(const float4*)(beta + 256 + lane * 4);
    float* rr = res + (long long)rl * HID;
    float4 o0, o1;
    o0.x = d[0] * rs * g0.x + b0.x; o0.y = d[1] * rs * g0.y + b0.y;
    o0.z = d[2] * rs * g0.z + b0.z; o0.w = d[3] * rs * g0.w + b0.w;
    o1.x = d[4] * rs * g1.x + b1.x; o1.y = d[5] * rs * g1.y + b1.y;
    o1.z = d[6] * rs * g1.z + b1.z; o1.w = d[7] * rs * g1.w + b1.w;
    *(float4*)(rr + lane * 4) = o0;
    *(float4*)(rr + 256 + lane * 4) = o1;
}

// ---------------------------------------------------------------------------
// 2) fp32 GEMM (unchanged — verified correct)
// ---------------------------------------------------------------------------
template <int MODE>
__launch_bounds__(256, 2)
__global__ void gemm_nt(const float* __restrict__ A, const float* __restrict__ B,
                        const float* __restrict__ bias1, const float* __restrict__ bias2,
                        float* __restrict__ C, int N) {
    __shared__ float As[16][132];
    __shared__ float Bs[16][132];
    int tid = threadIdx.x;
    int tx = tid & 15, ty = tid >> 4;
    int r0 = blockIdx.x * 128;
    int j0 = blockIdx.y * 128;
    int arow = tid >> 2, ac = (tid & 3) * 4;

    float acc[8][8] = {};

    for (int kt = 0; kt < 512; kt += 16) {
        float4 a0 = *(const float4*)(A + (long long)(r0 + arow) * 512 + kt + ac);
        float4 a1 = *(const float4*)(A + (long long)(r0 + arow + 64) * 512 + kt + ac);
        float4 b0 = *(const float4*)(B + (long long)(j0 + arow) * 512 + kt + ac);
        float4 b1 = *(const float4*)(B + (long long)(j0 + arow + 64) * 512 + kt + ac);
        __syncthreads();
        As[ac + 0][arow] = a0.x; As[ac + 1][arow] = a0.y;
        As[ac + 2][arow] = a0.z; As[ac + 3][arow] = a0.w;
        As[ac + 0][arow + 64] = a1.x; As[ac + 1][arow + 64] = a1.y;
        As[ac + 2][arow + 64] = a1.z; As[ac + 3][arow + 64] = a1.w;
        Bs[ac + 0][arow] = b0.x; Bs[ac + 1][arow] = b0.y;
        Bs[ac + 2][arow] = b0.z; Bs[ac + 3][arow] = b0.w;
        Bs[ac + 0][arow + 64] = b1.x; Bs[ac + 1][arow + 64] = b1.y;
        Bs[ac + 2][arow + 64] = b1.z; Bs[ac + 3][arow + 64] = b1.w;
        __syncthreads();
#pragma unroll
        for (int kk = 0; kk < 16; kk++) {
            float a[8], bb[8];
            *(float4*)(a)      = *(const float4*)&As[kk][ty * 8];
            *(float4*)(a + 4)  = *(const float4*)&As[kk][ty * 8 + 4];
            *(float4*)(bb)     = *(const float4*)&Bs[kk][tx * 8];
            *(float4*)(bb + 4) = *(const float4*)&Bs[kk][tx * 8 + 4];
#pragma unroll
            for (int i = 0; i < 8; i++)
#pragma unroll
                for (int j = 0; j < 8; j++) acc[i][j] += a[i] * bb[j];
        }
    }

    float bv[8];
#pragma unroll
    for (int jj = 0; jj < 8; jj++) {
        int j = j0 + tx * 8 + jj;
        bv[jj] = (MODE == 0) ? (bias1[j] + bias2[j]) : bias1[j];
    }
#pragma unroll
    for (int ii = 0; ii < 8; ii++) {
        long long r = r0 + ty * 8 + ii;
        float* crow = C + r * (long long)N + j0 + tx * 8;
        float v[8];
#pragma unroll
        for (int jj = 0; jj < 8; jj++) {
            float tv = acc[ii][jj] + bv[jj];
            if (MODE == 1) tv = tv * sigf(tv);
            v[jj] = tv;
        }
        float4 o0, o1;
        o0.x = v[0]; o0.y = v[1]; o0.z = v[2]; o0.w = v[3];
        o1.x = v[4]; o1.y = v[5]; o1.z = v[6]; o1.w = v[7];
        *(float4*)(crow) = o0;
        *(float4*)(crow + 4) = o1;
    }
}

// ---------------------------------------------------------------------------
// 3) LSTM scan, tagged-h protocol. 256 WGs x 256 thr (1/CU).
//    b=bid&7, w=bid>>3; thread (kg=tid&15, rq=tid>>4): slot=w*16+rq,
//    4 gate rows, k-window [kg*32, kg*32+32).
//
//    Publish: h packed with its step tag in ONE relaxed agent u64 store
//      h_tag[(t&1)][b][slot] = (t+1)<<32 | f32(h)
//    -> no vmcnt drain / no syncthreads / no separate flag on the produce path.
//    Consume (step t): each of 256 threads polls its 2 pairs of
//      h_tag[(t-1)&1][b][2tid..2tid+1] until tag==t (data rides the same
//    load), writes them to LDS (XOR-swizzled 16B granules), one barrier,
//    then lanes ds_read_b128 their 32-float windows.
//    Race-freedom by construction (parity double buffer): overwriting
//    parity p (tag t+1) requires observing all tags==t, which requires
//    every WG to have published h_{t-1}, which requires it to have
//    finished READING parity p (cooperative read-all precedes publish).
//    MALL traffic: 4KB/WG/step (vs 32KB direct) = ~1MB/step chip-wide.
// ---------------------------------------------------------------------------
__launch_bounds__(256, 1)
__global__ void scan_kernel(const float* __restrict__ W_hh,   // [2048][512]
                            const float* __restrict__ xp,     // [8*CH][2048]
                            const float* __restrict__ resv,   // [8*CH][512]
                            const float* __restrict__ gatev,  // [8*CH][512]
                            float* __restrict__ out,          // d_out
                            unsigned long long* __restrict__ h_tag, // [2][8][512]
                            float* __restrict__ c_buf,        // [8][512]
                            int t0, int chsh) {
    const int CH = 1 << chsh;
    int b = blockIdx.x & 7, w = blockIdx.x >> 3;
    int tid = threadIdx.x;
    int kg = tid & 15, rq = tid >> 4;
    int slot = w * 16 + rq;

    __shared__ __align__(16) float h_s[2][512];

    // wreg[g][j] = W_hh[g*512 + slot][kg*32 + j]
    float wreg[4][32];
#pragma unroll
    for (int g = 0; g < 4; g++) {
        const float* wr = W_hh + (long long)((g << 9) + slot) * 512 + (kg << 5);
#pragma unroll
        for (int q = 0; q < 8; q++) {
            float4 u = *(const float4*)(wr + q * 4);
            wreg[g][q * 4 + 0] = u.x; wreg[g][q * 4 + 1] = u.y;
            wreg[g][q * 4 + 2] = u.z; wreg[g][q * 4 + 3] = u.w;
        }
    }

    float c_reg = 0.0f;
    if (t0 > 0 && kg == 0) c_reg = c_buf[(b << 9) + slot];
    bool sync_ok = true;

    // poll assignment: this thread owns pairs (2tid, 2tid+1) of its batch
    const int pr0 = 2 * tid;
    // LDS write swizzle: granule n = tid>>1, phys granule pg_w
    const int n_w  = tid >> 1;
    const int pg_w = (n_w & ~7) | ((n_w ^ (n_w >> 3)) & 7);
    const int fi_w = (pg_w << 2) | (pr0 & 3);

    for (int i = 0; i < CH; i++) {
        int t = t0 + i;
        int rl = (b << chsh) + i;

        // prefetch epilogue operands (in flight during poll + matvec)
        float xpv0 = 0, xpv1 = 0, xpv2 = 0, xpv3 = 0, gv = 0, rv = 0;
        if (kg == 0) {
            const float* xr = xp + (long long)rl * 2048 + slot;
            xpv0 = xr[0]; xpv1 = xr[512]; xpv2 = xr[1024]; xpv3 = xr[1536];
            gv = gatev[rl * 512 + slot];
            rv = resv[rl * 512 + slot];
        }

        float acc0 = 0, acc1 = 0, acc2 = 0, acc3 = 0;
        if (t > 0) {
            const unsigned long long* tb = h_tag + ((t - 1) & 1) * 4096 + (b << 9);
            const unsigned exp = (unsigned)t;
            unsigned long long v0 = 0, v1 = 0;
            if (sync_ok) {
                bool g0 = false, g1 = false;
                int tries = 0;
                while (true) {
                    if (!g0) {
                        v0 = __hip_atomic_load(tb + pr0, __ATOMIC_RELAXED,
                                               __HIP_MEMORY_SCOPE_AGENT);
                        g0 = ((unsigned)(v0 >> 32) == exp);
                    }
                    if (!g1) {
                        v1 = __hip_atomic_load(tb + pr0 + 1, __ATOMIC_RELAXED,
                                               __HIP_MEMORY_SCOPE_AGENT);
                        g1 = ((unsigned)(v1 >> 32) == exp);
                    }
                    if (g0 && g1) break;
                    if (++tries > (1 << 15)) { sync_ok = false; break; }
                }
            } else {
                v0 = __hip_atomic_load(tb + pr0, __ATOMIC_RELAXED,
                                       __HIP_MEMORY_SCOPE_AGENT);
                v1 = __hip_atomic_load(tb + pr0 + 1, __ATOMIC_RELAXED,
                                       __HIP_MEMORY_SCOPE_AGENT);
            }
            int p = t & 1;
            *(float2*)&h_s[p][fi_w] =
                make_float2(__uint_as_float((unsigned)v0), __uint_as_float((unsigned)v1));
            __syncthreads();
            // window read, swizzled granules: logical n=8kg+q at phys 8kg+(q^(kg&7))
            float hv[32];
#pragma unroll
            for (int q = 0; q < 8; q++) {
                int pg = (kg << 3) + (q ^ (kg & 7));
                float4 u = *(const float4*)&h_s[p][pg << 2];
                hv[q * 4 + 0] = u.x; hv[q * 4 + 1] = u.y;
                hv[q * 4 + 2] = u.z; hv[q * 4 + 3] = u.w;
            }
#pragma unroll
            for (int j = 0; j < 32; j++) {
                acc0 += hv[j] * wreg[0][j];
                acc1 += hv[j] * wreg[1][j];
                acc2 += hv[j] * wreg[2][j];
                acc3 += hv[j] * wreg[3][j];
            }
            acc0 += __shfl_xor(acc0, 1, 64); acc0 += __shfl_xor(acc0, 2, 64);
            acc0 += __shfl_xor(acc0, 4, 64); acc0 += __shfl_xor(acc0, 8, 64);
            acc1 += __shfl_xor(acc1, 1, 64); acc1 += __shfl_xor(acc1, 2, 64);
            acc1 += __shfl_xor(acc1, 4, 64); acc1 += __shfl_xor(acc1, 8, 64);
            acc2 += __shfl_xor(acc2, 1, 64); acc2 += __shfl_xor(acc2, 2, 64);
            acc2 += __shfl_xor(acc2, 4, 64); acc2 += __shfl_xor(acc2, 8, 64);
            acc3 += __shfl_xor(acc3, 1, 64); acc3 += __shfl_xor(acc3, 2, 64);
            acc3 += __shfl_xor(acc3, 4, 64); acc3 += __shfl_xor(acc3, 8, 64);
        }

        if (kg == 0) {
            float iv = sigf(acc0 + xpv0);
            float fv = sigf(acc1 + xpv1);
            float gt = tanhf_(acc2 + xpv2);
            float ov = sigf(acc3 + xpv3);
            c_reg = fv * c_reg + iv * gt;
            float h = ov * tanhf_(c_reg);
            // publish: data+tag in one relaxed agent atomic (critical path ends here)
            unsigned long long pkt =
                ((unsigned long long)(unsigned)(t + 1) << 32) |
                (unsigned long long)__float_as_uint(h);
            __hip_atomic_store(h_tag + (t & 1) * 4096 + (b << 9) + slot, pkt,
                               __ATOMIC_RELAXED, __HIP_MEMORY_SCOPE_AGENT);
            // off critical path
            out[(long long)((b << 12) + t) * 512 + slot] = h * gv + rv;
            if (t == 4095) {
                out[16777216 + (b << 9) + slot] = h;            // hT
                out[16777216 + 4096 + (b << 9) + slot] = c_reg; // cT
            }
            if (i == CH - 1) c_buf[(b << 9) + slot] = c_reg;    // chunk carry
        }
    }
}

// ---------------------------------------------------------------------------
// launch: chunk T so the workspace fits ws_size.
// per-chunk floats: 8*CH*512 (res) + 8*CH*512 (gate) + 8*CH*2048 (xp)
// persistent: h_tag 8192 u64 (64KB) + c_buf 4096 f (16KB)
// ---------------------------------------------------------------------------
extern "C" void kernel_launch(void* const* d_in, const int* in_sizes, int n_in,
                              void* d_out, int out_size, void* d_ws, size_t ws_size,
                              hipStream_t stream) {
    const float* x     = (const float*)d_in[0];
    const float* W_ih  = (const float*)d_in[1];
    const float* W_hh  = (const float*)d_in[2];
    const float* b_ih  = (const float*)d_in[3];
    const float* b_hh  = (const float*)d_in[4];
    const float* gamma = (const float*)d_in[5];
    const float* beta  = (const float*)d_in[6];
    const float* W_lin = (const float*)d_in[7];
    const float* b_lin = (const float*)d_in[8];
    float* out = (float*)d_out;

    const size_t small_bytes = 8192ull * 8 + 4096ull * 4;  // h_tag + c_buf
    int CH = 256;
    for (int cand = 4096; cand >= 256; cand >>= 1) {
        if ((size_t)98304 * cand + small_bytes <= ws_size) { CH = cand; break; }
    }
    int chsh = 31 - __builtin_clz(CH);

    float* ws      = (float*)d_ws;
    float* res_ch  = ws;
    float* gate_ch = res_ch + (size_t)8 * CH * 512;
    float* xp_ch   = gate_ch + (size_t)8 * CH * 512;
    unsigned long long* h_tag = (unsigned long long*)(xp_ch + (size_t)8 * CH * 2048);
    float* c_buf   = (float*)(h_tag + 8192);

    init_tags_kernel<<<32, 256, 0, stream>>>(h_tag);

    int nchunks = 4096 / CH;
    for (int c = 0; c < nchunks; c++) {
        int t0 = c * CH;
        ln_kernel<<<8 * CH / 4, 256, 0, stream>>>(x, gamma, beta, res_ch, t0, chsh);
        gemm_nt<0><<<dim3(8 * CH / 128, 16), 256, 0, stream>>>(res_ch, W_ih, b_ih, b_hh,
                                                               xp_ch, 2048);
        gemm_nt<1><<<dim3(8 * CH / 128, 4), 256, 0, stream>>>(res_ch, W_lin, b_lin, b_lin,
                                                              gate_ch, 512);
        scan_kernel<<<256, 256, 0, stream>>>(W_hh, xp_ch, res_ch, gate_ch, out,
                                             h_tag, c_buf, t0, chsh);
    }
}